// Round 12
// baseline (160.864 us; speedup 1.0000x reference)
//
#include <hip/hip_runtime.h>
#include <hip/hip_bf16.h>

#define NROW 131072   // B*L
#define D 256
#define K 320
#define BN_EPS 1e-5f
#define FIXSCALE 16777216.0f   // 2^24 fixed-point for deterministic atomics

typedef _Float16 half8 __attribute__((ext_vector_type(8)));
typedef float f32x4 __attribute__((ext_vector_type(4)));

// ws layout:
//   u64 acc[512]   @ 0      (4 KB)
//   f32 meanb[256] @ 4096
//   f32 rsb[256]   @ 5120
//   f32 cnorm[320] @ 6144
//   f16 cbx        @ 8192   (320 KB) codebook fragments, chunk-contiguous:
//     tile nt(0..19), hl(0=hi,1=lo), ks(0..7): halfs at ((nt*2+hl)*8+ks)*512 + lane*8
//     -> chunk c (tiles 2c,2c+1) is the contiguous 32 KB at c*32768 bytes

// ---------------- kernel 0: zero the fixed-point accumulators ---------------
__global__ __launch_bounds__(256) void k_zero(unsigned long long* __restrict__ acc) {
  acc[threadIdx.x] = 0ull;
  acc[256 + threadIdx.x] = 0ull;
}

// ---------------- kernel 1: per-block channel partials -> fixed-point atomics
__global__ __launch_bounds__(256) void k_stats_partial(const float* __restrict__ x,
                                                       unsigned long long* __restrict__ acc) {
  const int d = threadIdx.x;
  const int blk = blockIdx.x;         // 512 blocks, 256 rows each
  const float* p = x + (size_t)blk * 256 * D + d;
  float s = 0.f, q = 0.f;
  #pragma unroll 4
  for (int r = 0; r < 256; ++r) {
    float v = p[(size_t)r * D];
    s += v;
    q = fmaf(v, v, q);
  }
  long long si = llrintf(s * FIXSCALE);
  long long qi = llrintf(q * FIXSCALE);
  atomicAdd(&acc[d],       (unsigned long long)si);
  atomicAdd(&acc[256 + d], (unsigned long long)qi);
}

// ---------------- kernel 2: finalize stats + codebook norms -----------------
__global__ __launch_bounds__(256) void k_stats_final(const unsigned long long* __restrict__ acc,
                                                     const float* __restrict__ cb,
                                                     float* __restrict__ meanb,
                                                     float* __restrict__ rsb,
                                                     float* __restrict__ cnorm) {
  const int t = threadIdx.x;
  if (blockIdx.x == 0) {
    double s = (double)(long long)acc[t]       / (double)FIXSCALE;
    double q = (double)(long long)acc[256 + t] / (double)FIXSCALE;
    double mean = s / (double)NROW;
    double var  = q / (double)NROW - mean * mean;
    meanb[t] = (float)mean;
    rsb[t]   = (float)(1.0 / sqrt(var + (double)BN_EPS));
  } else {
    for (int code = t; code < K; code += 256) {
      const float* c = cb + (size_t)code * D;
      float s = 0.f;
      for (int dd = 0; dd < D; ++dd) s = fmaf(c[dd], c[dd], s);
      cnorm[code] = s;
    }
  }
}

// ---------------- kernel 2b: split codebook to fp16 hi/lo fragments ---------
// MFMA B-fragment: lane l holds code = nt*16 + (l&15), k = ks*32 + (l>>4)*8..+8
__global__ __launch_bounds__(64) void k_cbprep(const float* __restrict__ cb,
                                               _Float16* __restrict__ cbx) {
  const int nt = blockIdx.x;   // 0..19
  const int ks = blockIdx.y;   // 0..7
  const int l  = threadIdx.x;  // 0..63
  const int code = nt * 16 + (l & 15);
  const int d0 = ks * 32 + (l >> 4) * 8;
  const float* src = cb + (size_t)code * D + d0;
  const size_t bh = ((size_t)(nt * 2 + 0) * 8 + ks) * 512 + l * 8;
  const size_t bl = ((size_t)(nt * 2 + 1) * 8 + ks) * 512 + l * 8;
  #pragma unroll
  for (int j = 0; j < 8; ++j) {
    float v = src[j];
    _Float16 h = (_Float16)v;
    _Float16 lo = (_Float16)(v - (float)h);
    cbx[bh + j] = h;
    cbx[bl + j] = lo;
  }
}

// ---------------- kernel 3: A-in-registers (32 rows/wave), B via LDS dbuf ---
// 512 blocks x 512 thr. Wave wv owns rows row0 + wv*32 .. +32 (2 x 16-row
// tiles) against ALL 320 codes. A frags (2 tiles x 8 ks x hi/lo) = 128 VGPRs
// irreducibly live -> forces the fat register tier; B-chunk LDS reads per
// FLOP halve vs the 16-row/wave version (R11 was LDS-BW-bound).
__global__ __launch_bounds__(512) void k_main(const float* __restrict__ x,
                                              const float* __restrict__ w,
                                              const float* __restrict__ bias,
                                              const float* __restrict__ cb,
                                              const float* __restrict__ meanb,
                                              const float* __restrict__ rsb,
                                              const float* __restrict__ cnorm,
                                              const _Float16* __restrict__ cbx,
                                              float* __restrict__ out) {
  __shared__ _Float16 Bbuf[2][16384];   // 2 x 32 KB code-chunks
  __shared__ float sxs[256];            // per-row |xb|^2
  __shared__ int bsel[256];

  const int t = threadIdx.x;
  const int lane = t & 63;
  const int wv = t >> 6;              // wave 0..7
  const int c15 = lane & 15;
  const int g = lane >> 4;
  const int row0 = (int)blockIdx.x * 256;

  // ---- cooperative B staging: chunk c = 32 KB contiguous, reg-staged ----
  float4 s0, s1, s2, s3;
  const char* stg_src = (const char*)cbx + (size_t)t * 16;
#define ISSUE(c) {                                                  \
    const char* p_ = stg_src + (size_t)(c) * 32768;                 \
    s0 = *(const float4*)(p_);                                      \
    s1 = *(const float4*)(p_ + 8192);                               \
    s2 = *(const float4*)(p_ + 16384);                              \
    s3 = *(const float4*)(p_ + 24576);                              \
  }
#define WRITE(b) {                                                  \
    char* q_ = (char*)Bbuf[b] + t * 16;                             \
    *(float4*)(q_)         = s0;                                    \
    *(float4*)(q_ + 8192)  = s1;                                    \
    *(float4*)(q_ + 16384) = s2;                                    \
    *(float4*)(q_ + 24576) = s3;                                    \
  }

  ISSUE(0);

  // ---- x -> A fragments in registers (normalize + fp16 hi/lo split) ----
  // lane l, tile i: row = row0 + wv*32 + i*16 + (l&15), dims g*8 + ks*32 ..+8
  half8 ah[2][8], al[2][8];
  float accq0 = 0.f, accq1 = 0.f;
  {
    const int dbase = g * 8;
    const float* xp0 = x + (size_t)(row0 + wv * 32 + c15) * D + dbase;
    const float* xp1 = x + (size_t)(row0 + wv * 32 + 16 + c15) * D + dbase;
    #pragma unroll
    for (int ks = 0; ks < 8; ++ks) {
      const int d0 = dbase + ks * 32;
      float4 m0 = *(const float4*)(meanb + d0);
      float4 m1 = *(const float4*)(meanb + d0 + 4);
      float4 r0 = *(const float4*)(rsb + d0);
      float4 r1 = *(const float4*)(rsb + d0 + 4);
      float4 w0 = *(const float4*)(w + d0);
      float4 w1 = *(const float4*)(w + d0 + 4);
      float4 b0 = *(const float4*)(bias + d0);
      float4 b1 = *(const float4*)(bias + d0 + 4);
      // tile 0
      {
        float4 xa = *(const float4*)(xp0 + ks * 32);
        float4 xb2 = *(const float4*)(xp0 + ks * 32 + 4);
        float o0 = ((xa.x - m0.x) * r0.x) * w0.x + b0.x;
        float o1 = ((xa.y - m0.y) * r0.y) * w0.y + b0.y;
        float o2 = ((xa.z - m0.z) * r0.z) * w0.z + b0.z;
        float o3 = ((xa.w - m0.w) * r0.w) * w0.w + b0.w;
        float o4 = ((xb2.x - m1.x) * r1.x) * w1.x + b1.x;
        float o5 = ((xb2.y - m1.y) * r1.y) * w1.y + b1.y;
        float o6 = ((xb2.z - m1.z) * r1.z) * w1.z + b1.z;
        float o7 = ((xb2.w - m1.w) * r1.w) * w1.w + b1.w;
        accq0 = fmaf(o0, o0, accq0); accq0 = fmaf(o1, o1, accq0);
        accq0 = fmaf(o2, o2, accq0); accq0 = fmaf(o3, o3, accq0);
        accq0 = fmaf(o4, o4, accq0); accq0 = fmaf(o5, o5, accq0);
        accq0 = fmaf(o6, o6, accq0); accq0 = fmaf(o7, o7, accq0);
        _Float16 h;
        h = (_Float16)o0; ah[0][ks][0] = h; al[0][ks][0] = (_Float16)(o0 - (float)h);
        h = (_Float16)o1; ah[0][ks][1] = h; al[0][ks][1] = (_Float16)(o1 - (float)h);
        h = (_Float16)o2; ah[0][ks][2] = h; al[0][ks][2] = (_Float16)(o2 - (float)h);
        h = (_Float16)o3; ah[0][ks][3] = h; al[0][ks][3] = (_Float16)(o3 - (float)h);
        h = (_Float16)o4; ah[0][ks][4] = h; al[0][ks][4] = (_Float16)(o4 - (float)h);
        h = (_Float16)o5; ah[0][ks][5] = h; al[0][ks][5] = (_Float16)(o5 - (float)h);
        h = (_Float16)o6; ah[0][ks][6] = h; al[0][ks][6] = (_Float16)(o6 - (float)h);
        h = (_Float16)o7; ah[0][ks][7] = h; al[0][ks][7] = (_Float16)(o7 - (float)h);
      }
      // tile 1
      {
        float4 xa = *(const float4*)(xp1 + ks * 32);
        float4 xb2 = *(const float4*)(xp1 + ks * 32 + 4);
        float o0 = ((xa.x - m0.x) * r0.x) * w0.x + b0.x;
        float o1 = ((xa.y - m0.y) * r0.y) * w0.y + b0.y;
        float o2 = ((xa.z - m0.z) * r0.z) * w0.z + b0.z;
        float o3 = ((xa.w - m0.w) * r0.w) * w0.w + b0.w;
        float o4 = ((xb2.x - m1.x) * r1.x) * w1.x + b1.x;
        float o5 = ((xb2.y - m1.y) * r1.y) * w1.y + b1.y;
        float o6 = ((xb2.z - m1.z) * r1.z) * w1.z + b1.z;
        float o7 = ((xb2.w - m1.w) * r1.w) * w1.w + b1.w;
        accq1 = fmaf(o0, o0, accq1); accq1 = fmaf(o1, o1, accq1);
        accq1 = fmaf(o2, o2, accq1); accq1 = fmaf(o3, o3, accq1);
        accq1 = fmaf(o4, o4, accq1); accq1 = fmaf(o5, o5, accq1);
        accq1 = fmaf(o6, o6, accq1); accq1 = fmaf(o7, o7, accq1);
        _Float16 h;
        h = (_Float16)o0; ah[1][ks][0] = h; al[1][ks][0] = (_Float16)(o0 - (float)h);
        h = (_Float16)o1; ah[1][ks][1] = h; al[1][ks][1] = (_Float16)(o1 - (float)h);
        h = (_Float16)o2; ah[1][ks][2] = h; al[1][ks][2] = (_Float16)(o2 - (float)h);
        h = (_Float16)o3; ah[1][ks][3] = h; al[1][ks][3] = (_Float16)(o3 - (float)h);
        h = (_Float16)o4; ah[1][ks][4] = h; al[1][ks][4] = (_Float16)(o4 - (float)h);
        h = (_Float16)o5; ah[1][ks][5] = h; al[1][ks][5] = (_Float16)(o5 - (float)h);
        h = (_Float16)o6; ah[1][ks][6] = h; al[1][ks][6] = (_Float16)(o6 - (float)h);
        h = (_Float16)o7; ah[1][ks][7] = h; al[1][ks][7] = (_Float16)(o7 - (float)h);
      }
    }
  }
  // row sums: butterfly over the 4 k-slices (lanes xor 16, 32); deterministic
  {
    float v0 = accq0 + __shfl_xor(accq0, 16);
    float sx0 = v0 + __shfl_xor(v0, 32);
    float v1 = accq1 + __shfl_xor(accq1, 16);
    float sx1 = v1 + __shfl_xor(v1, 32);
    if (lane < 16) {
      sxs[wv * 32 + lane]      = sx0;
      sxs[wv * 32 + 16 + lane] = sx1;
    }
  }

  WRITE(0);                           // land chunk 0
  ISSUE(1);                           // drained by the barrier below
  __syncthreads();                    // buf0 + sxs visible

  // ---- chunk loop: 10 x (32 codes); argmin folded per chunk ----
  float bv[2][4];
  int   bix[2][4];
  #pragma unroll
  for (int i = 0; i < 2; ++i)
    #pragma unroll
    for (int r = 0; r < 4; ++r) { bv[i][r] = 3.4e38f; bix[i][r] = 0x7fffffff; }

  float sxr[2][4];
  #pragma unroll
  for (int i = 0; i < 2; ++i)
    #pragma unroll
    for (int r = 0; r < 4; ++r) sxr[i][r] = sxs[wv * 32 + i * 16 + g * 4 + r];

  for (int c = 0; c < 10; ++c) {
    // WRITE first (consumes s0-s3, landed), then ISSUE next (flies under MFMA)
    if (c + 1 < 10) WRITE((c + 1) & 1);
    if (c + 2 < 10) ISSUE(c + 2);

    const _Float16* bb = Bbuf[c & 1] + lane * 8;
    f32x4 acc[2][2];
    #pragma unroll
    for (int i = 0; i < 2; ++i)
      #pragma unroll
      for (int tt = 0; tt < 2; ++tt) acc[i][tt] = (f32x4){0.f, 0.f, 0.f, 0.f};

    #pragma unroll
    for (int tt = 0; tt < 2; ++tt) {
      #pragma unroll
      for (int ks = 0; ks < 8; ++ks) {
        half8 bh = *(const half8*)(bb + ((tt * 2 + 0) * 8 + ks) * 512);
        half8 bl = *(const half8*)(bb + ((tt * 2 + 1) * 8 + ks) * 512);
        #pragma unroll
        for (int i = 0; i < 2; ++i) {
          acc[i][tt] = __builtin_amdgcn_mfma_f32_16x16x32_f16(ah[i][ks], bh, acc[i][tt], 0, 0, 0);
          acc[i][tt] = __builtin_amdgcn_mfma_f32_16x16x32_f16(ah[i][ks], bl, acc[i][tt], 0, 0, 0);
          acc[i][tt] = __builtin_amdgcn_mfma_f32_16x16x32_f16(al[i][ks], bh, acc[i][tt], 0, 0, 0);
        }
      }
    }

    // d2 = (sx - 2*dot) + cn  (exact rounding-matched expression)
    // C/D layout: col = lane&15 (code), row = (lane>>4)*4 + r
    #pragma unroll
    for (int tt = 0; tt < 2; ++tt) {
      const int code = c * 32 + tt * 16 + c15;
      const float cn = cnorm[code];
      #pragma unroll
      for (int i = 0; i < 2; ++i) {
        #pragma unroll
        for (int r = 0; r < 4; ++r) {
          const float d2 = (sxr[i][r] - 2.0f * acc[i][tt][r]) + cn;
          if (d2 < bv[i][r] || (d2 == bv[i][r] && code < bix[i][r])) {
            bv[i][r] = d2; bix[i][r] = code;
          }
        }
      }
    }
    if (c < 9) __syncthreads();       // chunk c+1 visible
  }

  // ---- butterfly argmin across the 16 lanes (columns) ----
  #pragma unroll
  for (int off = 8; off >= 1; off >>= 1) {
    #pragma unroll
    for (int i = 0; i < 2; ++i)
      #pragma unroll
      for (int r = 0; r < 4; ++r) {
        const float ov = __shfl_xor(bv[i][r], off);
        const int   oi = __shfl_xor(bix[i][r], off);
        if (ov < bv[i][r] || (ov == bv[i][r] && oi < bix[i][r])) {
          bv[i][r] = ov; bix[i][r] = oi;
        }
      }
  }
  if (c15 == 0) {
    #pragma unroll
    for (int i = 0; i < 2; ++i)
      #pragma unroll
      for (int r = 0; r < 4; ++r) {
        const int row = wv * 32 + i * 16 + g * 4 + r;   // local row 0..255
        bsel[row] = bix[i][r];
        out[(size_t)NROW * D + row0 + row] = (float)bix[i][r];
      }
  }
  __syncthreads();

  // ---- gather chosen codes (exact f32 copy), 2 threads per row ----
  {
    const int lr = t >> 1;            // 0..255
    const int q = t & 1;
    const int code = bsel[lr];
    const float* cp = cb + (size_t)code * D;
    float* op = out + (size_t)(row0 + lr) * D;
    #pragma unroll
    for (int e = 0; e < 16; ++e) {
      *(float4*)(op + (e * 2 + q) * 4) = *(const float4*)(cp + (e * 2 + q) * 4);
    }
  }
#undef ISSUE
#undef WRITE
}

extern "C" void kernel_launch(void* const* d_in, const int* in_sizes, int n_in,
                              void* d_out, int out_size, void* d_ws, size_t ws_size,
                              hipStream_t stream) {
  const float* x    = (const float*)d_in[0];
  const float* w    = (const float*)d_in[1];
  const float* bias = (const float*)d_in[2];
  const float* cb   = (const float*)d_in[3];
  float* out = (float*)d_out;

  unsigned long long* acc = (unsigned long long*)d_ws;
  float* meanb = (float*)((char*)d_ws + 4096);
  float* rsb   = meanb + 256;
  float* cnorm = rsb + 256;
  _Float16* cbx = (_Float16*)((char*)d_ws + 8192);   // 320 KB

  k_zero<<<1, 256, 0, stream>>>(acc);
  k_cbprep<<<dim3(20, 8), 64, 0, stream>>>(cb, cbx);
  k_stats_partial<<<512, 256, 0, stream>>>(x, acc);
  k_stats_final<<<2, 256, 0, stream>>>(acc, cb, meanb, rsb, cnorm);
  k_main<<<NROW / 256, 512, 0, stream>>>(x, w, bias, cb, meanb, rsb, cnorm, cbx, out);
}